// Round 5
// baseline (387.122 us; speedup 1.0000x reference)
//
#include <hip/hip_runtime.h>

#define G_ 100
#define T_ 24
#define GP1 101
#define TILE (G_ * T_)        // 2400 floats per (b,pass)
#define VPB (TILE / 4)        // 600 float4 per pass
#define BLOCK 256
#define NACT (2 * T_)         // 48 scan threads (both passes, one wave)
#define NIT 3                 // ceil(600/256)

typedef float vfloat4 __attribute__((ext_vector_type(4)));

// Batched in-LDS merit-order chunk: batch N LDS cap reads (MLP), then the
// serial clip-scan writing alloc in-place over cap (each g touched once).
template<int N>
__device__ __forceinline__ void scan_chunk(int k0,
    float* __restrict__ tile, const int* __restrict__ ordp,
    const float* __restrict__ prp, float dem,
    float& before, float& objp, float& slackv)
{
    int gg[N]; float pr[N], cap[N];
#pragma unroll
    for (int j = 0; j < N; ++j) { gg[j] = ordp[k0 + j]; pr[j] = prp[k0 + j]; }
#pragma unroll
    for (int j = 0; j < N; ++j) {
        int gl = (gg[j] < G_) ? gg[j] : 0;          // slack slot: dummy read
        cap[j] = tile[gl * T_];
    }
#pragma unroll
    for (int j = 0; j < N; ++j) {
        float c = (gg[j] == G_) ? dem : cap[j];
        float a = fminf(fmaxf(dem - before, 0.f), c);
        before += c;
        objp = fmaf(pr[j], a, objp);
        if (gg[j] == G_) slackv = a;
        else             tile[gg[j] * T_] = a;      // in-place, own column only
    }
}

__global__ __launch_bounds__(BLOCK, 7) void dispatch_kernel(
    const float* __restrict__ R_up, const float* __restrict__ R_dn,
    const float* __restrict__ omega, const float* __restrict__ b_G,
    const float* __restrict__ voll, const float* __restrict__ vosp,
    const float* __restrict__ ru, const float* __restrict__ rd,
    float* __restrict__ out, int B)
{
    __shared__ float s_tile[2 * TILE];      // 19200 B, in-place cap -> alloc
    __shared__ float s_praw[2][GP1];
    __shared__ int   s_ord[2][GP1];
    __shared__ float s_pr[2][GP1];
    __shared__ float s_obj[NACT];

    const int tid = threadIdx.x;
    const int b   = blockIdx.x;
    const size_t bgt = (size_t)B * TILE;

    // ---- raw price vectors ----
    if (tid < GP1) {
        if (tid < G_) {
            float bg = b_G[tid];
            s_praw[0][tid] = ru[0] * bg;    // c_up
            s_praw[1][tid] = rd[0] * bg;    // c_dn
        } else {
            s_praw[0][tid] = voll[0];
            s_praw[1][tid] = vosp[0];
        }
    }
    __syncthreads();

    // ---- issue ALL global loads first (coalesced float4, trivial indexing) ----
    vfloat4 buf[2][NIT];
    {
        const vfloat4* s0 = (const vfloat4*)R_up + (size_t)b * VPB;
        const vfloat4* s1 = (const vfloat4*)R_dn + (size_t)b * VPB;
#pragma unroll
        for (int it = 0; it < NIT; ++it) {
            int i = tid + it * BLOCK;
            if (i < VPB) { buf[0][it] = s0[i]; buf[1][it] = s1[i]; }
        }
    }
    float om = 0.f;
    if (tid < NACT) om = omega[(size_t)b * T_ + (tid % T_)];

    // ---- stable rank-sort (VALU; overlaps in-flight loads) ----
    if (tid < GP1) {
        float mu = s_praw[0][tid], md = s_praw[1][tid];
        int r0 = 0, r1 = 0;
        for (int j = 0; j < GP1; ++j) {
            float vu = s_praw[0][j], vd = s_praw[1][j];
            r0 += (vu < mu) || (vu == mu && j < tid);   // == jnp.argsort stable
            r1 += (vd < md) || (vd == md && j < tid);
        }
        s_ord[0][r0] = tid; s_pr[0][r0] = mu;
        s_ord[1][r1] = tid; s_pr[1][r1] = md;
    }

    // ---- registers -> LDS ----
#pragma unroll
    for (int it = 0; it < NIT; ++it) {
        int i = tid + it * BLOCK;
        if (i < VPB) {
            *(vfloat4*)&s_tile[i * 4]        = buf[0][it];
            *(vfloat4*)&s_tile[TILE + i * 4] = buf[1][it];
        }
    }
    __syncthreads();

    // ---- merit-order scan, entirely in LDS (one wave: 48 lanes) ----
    if (tid < NACT) {
        const int p = tid / T_;
        const int t = tid - p * T_;
        const float dem = p ? fmaxf(-om, 0.f) : fmaxf(om, 0.f);
        float* __restrict__ tile = &s_tile[p * TILE + t];
        const int*   __restrict__ ordp = s_ord[p];
        const float* __restrict__ prp  = s_pr[p];
        float before = 0.f, objp = 0.f, slackv = 0.f;
        scan_chunk<16>( 0, tile, ordp, prp, dem, before, objp, slackv);
        scan_chunk<16>(16, tile, ordp, prp, dem, before, objp, slackv);
        scan_chunk<16>(32, tile, ordp, prp, dem, before, objp, slackv);
        scan_chunk<16>(48, tile, ordp, prp, dem, before, objp, slackv);
        scan_chunk<16>(64, tile, ordp, prp, dem, before, objp, slackv);
        scan_chunk<16>(80, tile, ordp, prp, dem, before, objp, slackv);
        scan_chunk< 5>(96, tile, ordp, prp, dem, before, objp, slackv);

        out[2 * bgt + (size_t)p * B * T_ + (size_t)b * T_ + t] = slackv;
        s_obj[tid] = objp;
    }
    __syncthreads();

    // ---- rt_obj: complete per block (both passes) -> single plain store ----
    if (tid == 0) {
        float s = 0.f;
        for (int j = 0; j < NACT; ++j) s += s_obj[j];
        out[2 * bgt + 2 * (size_t)B * T_ + b] = s;
    }

    // ---- LDS -> global, coalesced PLAIN float4 stores (L2 write-combine) ----
    {
        vfloat4* d0 = (vfloat4*)out + (size_t)b * VPB;
        vfloat4* d1 = (vfloat4*)(out + bgt) + (size_t)b * VPB;
#pragma unroll
        for (int it = 0; it < NIT; ++it) {
            int i = tid + it * BLOCK;
            if (i < VPB) {
                d0[i] = *(const vfloat4*)&s_tile[i * 4];
                d1[i] = *(const vfloat4*)&s_tile[TILE + i * 4];
            }
        }
    }
}

extern "C" void kernel_launch(void* const* d_in, const int* in_sizes, int n_in,
                              void* d_out, int out_size, void* d_ws, size_t ws_size,
                              hipStream_t stream)
{
    const float* R_up  = (const float*)d_in[0];
    const float* R_dn  = (const float*)d_in[1];
    const float* omega = (const float*)d_in[2];
    const float* b_G   = (const float*)d_in[3];
    const float* voll  = (const float*)d_in[4];
    const float* vosp  = (const float*)d_in[5];
    const float* ru    = (const float*)d_in[6];
    const float* rd    = (const float*)d_in[7];

    const int B = in_sizes[0] / TILE;
    float* out = (float*)d_out;

    dispatch_kernel<<<B, BLOCK, 0, stream>>>(
        R_up, R_dn, omega, b_G, voll, vosp, ru, rd, out, B);
}

// Round 6
// 166.497 us; speedup vs baseline: 2.3251x; 2.3251x over previous
//
#include <hip/hip_runtime.h>

#define G_ 100
#define T_ 24
#define GP1 101
#define TILE (G_ * T_)        // 2400 floats per (b,pass) tile
#define VPB (TILE / 4)        // 600 float4 per tile
#define BLOCK 256             // 4 waves; wave w handles tile tau = blk*4+w
#define WPB 4

typedef float vfloat4 __attribute__((ext_vector_type(4)));

// One block, once: prices + stable rank-sort (== jnp.argsort) into workspace.
__global__ void setup_sort_kernel(const float* __restrict__ b_G,
                                  const float* __restrict__ voll,
                                  const float* __restrict__ vosp,
                                  const float* __restrict__ ru,
                                  const float* __restrict__ rd,
                                  int* __restrict__ order_out,     // [2][101]
                                  float* __restrict__ price_out)   // [2][101]
{
    __shared__ float pu[GP1], pd[GP1];
    int i = threadIdx.x;
    if (i < GP1) {
        if (i < G_) { float bg = b_G[i]; pu[i] = ru[0] * bg; pd[i] = rd[0] * bg; }
        else        { pu[i] = voll[0];   pd[i] = vosp[0]; }
    }
    __syncthreads();
    if (i < GP1) {
        float mu = pu[i], md = pd[i];
        int r0 = 0, r1 = 0;
        for (int j = 0; j < GP1; ++j) {
            float vu = pu[j], vd = pd[j];
            r0 += (vu < mu) || (vu == mu && j < i);
            r1 += (vd < md) || (vd == md && j < i);
        }
        order_out[r0] = i;        price_out[r0] = mu;
        order_out[GP1 + r1] = i;  price_out[GP1 + r1] = md;
    }
}

// Batched in-LDS merit-order chunk; ord/price come from global ws (scalar
// addressed, L1/sL1-hot). In-place cap -> alloc (each g touched exactly once).
template<int N>
__device__ __forceinline__ void scan_chunk(int k0,
    float* __restrict__ tile, const int* __restrict__ ordp,
    const float* __restrict__ prp, float dem,
    float& before, float& objp, float& slackv)
{
    int gg[N]; float pr[N], cap[N];
#pragma unroll
    for (int j = 0; j < N; ++j) { gg[j] = ordp[k0 + j]; pr[j] = prp[k0 + j]; }
#pragma unroll
    for (int j = 0; j < N; ++j) {
        int gl = (gg[j] < G_) ? gg[j] : 0;          // slack slot: dummy read
        cap[j] = tile[gl * T_];
    }
#pragma unroll
    for (int j = 0; j < N; ++j) {
        float c = (gg[j] == G_) ? dem : cap[j];
        float a = fminf(fmaxf(dem - before, 0.f), c);
        before += c;
        objp = fmaf(pr[j], a, objp);
        if (gg[j] == G_) slackv = a;
        else             tile[gg[j] * T_] = a;      // own column only
    }
}

__global__ __launch_bounds__(BLOCK, 4) void dispatch_kernel(
    const float* __restrict__ R_up, const float* __restrict__ R_dn,
    const float* __restrict__ omega,
    const int* __restrict__ ord_ws, const float* __restrict__ pr_ws,
    float* __restrict__ out, int B)
{
    __shared__ float s_tile[WPB * TILE];            // 38400 B -> 4 blocks/CU
    __shared__ float s_obj[WPB];

    const int tid  = threadIdx.x;
    const int w    = tid >> 6;                      // wave 0..3
    const int lane = tid & 63;
    // tau = blk*4 + w ; b = tau>>1 ; p = tau&1  (wave-uniform -> force SGPR)
    const int b = __builtin_amdgcn_readfirstlane((blockIdx.x * WPB + w) >> 1);
    const int p = __builtin_amdgcn_readfirstlane(w & 1);

    const size_t bgt = (size_t)B * TILE;

    // ---- wave-private coalesced load: 9600 B contiguous, 10 float4 insts ----
    const vfloat4* __restrict__ src =
        (const vfloat4*)(p ? R_dn : R_up) + (size_t)b * VPB;
    vfloat4 buf[10];
#pragma unroll
    for (int j = 0; j < 9; ++j) buf[j] = src[lane + j * 64];
    if (lane < VPB - 576) buf[9] = src[lane + 576];

    float* __restrict__ tw = &s_tile[w * TILE];
#pragma unroll
    for (int j = 0; j < 9; ++j) *(vfloat4*)&tw[(lane + j * 64) * 4] = buf[j];
    if (lane < VPB - 576)       *(vfloat4*)&tw[(lane + 576) * 4]    = buf[9];
    __syncthreads();

    // ---- merit-order scan in LDS (24 lanes per wave) ----
    float objp = 0.f;
    if (lane < T_) {
        const float om  = omega[(size_t)b * T_ + lane];
        const float dem = p ? fmaxf(-om, 0.f) : fmaxf(om, 0.f);
        float* __restrict__ tile = tw + lane;
        const int*   __restrict__ ordp = ord_ws + p * GP1;
        const float* __restrict__ prp  = pr_ws  + p * GP1;
        float before = 0.f, slackv = 0.f;
        scan_chunk<16>( 0, tile, ordp, prp, dem, before, objp, slackv);
        scan_chunk<16>(16, tile, ordp, prp, dem, before, objp, slackv);
        scan_chunk<16>(32, tile, ordp, prp, dem, before, objp, slackv);
        scan_chunk<16>(48, tile, ordp, prp, dem, before, objp, slackv);
        scan_chunk<16>(64, tile, ordp, prp, dem, before, objp, slackv);
        scan_chunk<16>(80, tile, ordp, prp, dem, before, objp, slackv);
        scan_chunk< 5>(96, tile, ordp, prp, dem, before, objp, slackv);
        out[2 * bgt + (size_t)p * B * T_ + (size_t)b * T_ + lane] = slackv;
    }

    // ---- rt_obj: wave butterfly-reduce, then pair up+dn within the block ----
#pragma unroll
    for (int off = 32; off; off >>= 1) objp += __shfl_xor(objp, off, 64);
    if (lane == 0) s_obj[w] = objp;
    __syncthreads();                                // also orders scan LDS writes
    if (tid == 0)
        out[2 * bgt + 2 * (size_t)B * T_ + 2 * blockIdx.x]     = s_obj[0] + s_obj[1];
    if (tid == 64)
        out[2 * bgt + 2 * (size_t)B * T_ + 2 * blockIdx.x + 1] = s_obj[2] + s_obj[3];

    // ---- wave-private coalesced store (plain; L2 write-combine) ----
    vfloat4* __restrict__ dst = (vfloat4*)out + ((size_t)p * B + b) * VPB;
#pragma unroll
    for (int j = 0; j < 9; ++j)
        dst[lane + j * 64] = *(const vfloat4*)&tw[(lane + j * 64) * 4];
    if (lane < VPB - 576)
        dst[lane + 576] = *(const vfloat4*)&tw[(lane + 576) * 4];
}

extern "C" void kernel_launch(void* const* d_in, const int* in_sizes, int n_in,
                              void* d_out, int out_size, void* d_ws, size_t ws_size,
                              hipStream_t stream)
{
    const float* R_up  = (const float*)d_in[0];
    const float* R_dn  = (const float*)d_in[1];
    const float* omega = (const float*)d_in[2];
    const float* b_G   = (const float*)d_in[3];
    const float* voll  = (const float*)d_in[4];
    const float* vosp  = (const float*)d_in[5];
    const float* ru    = (const float*)d_in[6];
    const float* rd    = (const float*)d_in[7];

    const int B = in_sizes[0] / TILE;
    float* out = (float*)d_out;

    int*   ord_ws = (int*)d_ws;
    float* pr_ws  = (float*)((char*)d_ws + 2 * GP1 * sizeof(int));

    setup_sort_kernel<<<1, 128, 0, stream>>>(b_G, voll, vosp, ru, rd, ord_ws, pr_ws);

    // 2B tiles, 4 waves/block -> exact grid (B multiple of 2)
    dispatch_kernel<<<(2 * B) / WPB, BLOCK, 0, stream>>>(
        R_up, R_dn, omega, ord_ws, pr_ws, out, B);
}